// Round 7
// baseline (754.399 us; speedup 1.0000x reference)
//
#include <hip/hip_runtime.h>
#include <hip/hip_fp16.h>

// ---------------------------------------------------------------------------
// MaskedGNN: 6-layer GCN, weight-free scaled-hidden formulation.
//  Store H' = dis * h  (fp16). Per layer:
//    z_i = dis_i * ( sum_{src in N(i)} H'_src + H'_i )   [pure gather-sum]
//    h_next' = dis * relu(z @ W + b)
//  CSR stores ONLY src index (4B/edge), built via TWO-PASS radix partition
//  (bucket = dst>>7) so final scatter writes are L2-local and line-merged.
//  GEMM: MFMA f32_16x16x32_f16, W split hi/lo fp16 (W exact), fp32 accum,
//  in-place. Last GEMM fuses the decoder matvec.
// ---------------------------------------------------------------------------

#define HW 128  // hidden width

typedef _Float16 f16x8 __attribute__((ext_vector_type(8)));
typedef float f32x4 __attribute__((ext_vector_type(4)));

// ---------------- CSR build ----------------
__global__ void k_zero_i32(int* __restrict__ a, int n) {
    int i = blockIdx.x * 256 + threadIdx.x;
    if (i < n) a[i] = 0;
}

// deg histogram + per-shard bucket histogram (shard = blockIdx&7 ~ XCD)
__global__ void k_hist(const int* __restrict__ dstA, int* __restrict__ deg,
                       int* __restrict__ scnt, int nb, int e) {
    int i = blockIdx.x * 256 + threadIdx.x;
    if (i >= e) return;
    int d = dstA[i];
    atomicAdd(&deg[d], 1);
    atomicAdd(&scnt[(blockIdx.x & 7) * nb + (d >> 7)], 1);
}

// scan_a also produces dis = rsqrt(1+deg)
__global__ void k_scan_a(const int* __restrict__ deg, int* __restrict__ tmp,
                         int* __restrict__ bsum, float* __restrict__ dis, int n) {
    __shared__ int s[256];
    int t = threadIdx.x;
    int i = blockIdx.x * 256 + t;
    int d0 = (i < n) ? deg[i] : 0;
    s[t] = d0;
    __syncthreads();
    for (int off = 1; off < 256; off <<= 1) {
        int v = (t >= off) ? s[t - off] : 0;
        __syncthreads();
        s[t] += v;
        __syncthreads();
    }
    if (i < n) {
        tmp[i] = s[t];
        dis[i] = rsqrtf(1.0f + (float)d0);
    }
    if (t == 255) bsum[blockIdx.x] = s[255];
}

__global__ void k_scan_b(int* __restrict__ bsum, int nb) {
    __shared__ int s[512];
    int t = threadIdx.x;
    s[t] = (t < nb) ? bsum[t] : 0;
    __syncthreads();
    for (int off = 1; off < 512; off <<= 1) {
        int v = (t >= off) ? s[t - off] : 0;
        __syncthreads();
        s[t] += v;
        __syncthreads();
    }
    if (t < nb) bsum[t] = s[t];
}

__global__ void k_scan_c(const int* __restrict__ tmp, const int* __restrict__ deg,
                         const int* __restrict__ bsum, int* __restrict__ row_start,
                         int* __restrict__ cursor, int n, int etot) {
    int i = blockIdx.x * 256 + threadIdx.x;
    if (i < n) {
        int off = blockIdx.x ? bsum[blockIdx.x - 1] : 0;
        row_start[i] = tmp[i] - deg[i] + off;  // exclusive scan
        cursor[i] = 0;
    }
    if (i == 0) row_start[n] = etot;
}

// staging cursors: bucket-major, shards concatenated within bucket region
__global__ void k_soff(const int* __restrict__ scnt, const int* __restrict__ row_start,
                       int* __restrict__ soff, int nb) {
    int b = blockIdx.x * 256 + threadIdx.x;
    if (b >= nb) return;
    int base = row_start[b << 7];
#pragma unroll
    for (int s = 0; s < 8; ++s) {
        soff[s * nb + b] = base;
        base += scnt[s * nb + b];
    }
}

// pass 1: partition edges into bucket-major staging (dense per-shard streams)
__global__ void k_part(const int* __restrict__ srcA, const int* __restrict__ dstA,
                       int* __restrict__ soff, int2* __restrict__ stage,
                       int nb, int e) {
    int i = blockIdx.x * 256 + threadIdx.x;
    if (i >= e) return;
    int d = dstA[i];
    int s = srcA[i];
    int p = atomicAdd(&soff[(blockIdx.x & 7) * nb + (d >> 7)], 1);
    stage[p] = make_int2(s, d);
}

// pass 2: bucket-local scatter (write lands near the sequential read position).
// XCD-bijective block swizzle keeps each bucket window on one XCD's L2.
__global__ void k_scatter2(const int2* __restrict__ stage,
                           const int* __restrict__ row_start, int* __restrict__ cursor,
                           int* __restrict__ csr, int e) {
    int nwg = gridDim.x;
    int q = nwg >> 3, r = nwg & 7;
    int xcd = blockIdx.x & 7, idx = blockIdx.x >> 3;
    int wgid = (xcd < r ? xcd * (q + 1) : r * (q + 1) + (xcd - r) * q) + idx;
    int i = wgid * 256 + threadIdx.x;
    if (i >= e) return;
    int2 sd = stage[i];
    int p = atomicAdd(&cursor[sd.y], 1);
    csr[row_start[sd.y] + p] = sd.x;
}

// ---------------- input prescale: x4[i] = dis_i * x_i (padded to float4) ----
__global__ void k_prep_x(const float* __restrict__ x, const float* __restrict__ dis,
                         float4* __restrict__ x4, int n) {
    int i = blockIdx.x * 256 + threadIdx.x;
    if (i >= n) return;
    float d = dis[i];
    x4[i] = make_float4(x[i * 3 + 0] * d, x[i * 3 + 1] * d, x[i * 3 + 2] * d, 0.f);
}

// ---------------- W prep: transpose + hi/lo fp16 split ----------------
__global__ void k_prep_wt(const float* __restrict__ Wp, __half* __restrict__ WTh,
                          __half* __restrict__ WTl, int total) {
    int t = blockIdx.x * 256 + threadIdx.x;
    if (t >= total) return;
    int l = t >> 14;
    int kc = t & 16383;
    int k = kc >> 7, c = kc & 127;
    float w = Wp[t];
    __half hi = __float2half_rn(w);
    __half lo = __float2half_rn(w - __half2float(hi));
    size_t o = ((size_t)l << 14) + (size_t)c * HW + k;
    WTh[o] = hi;
    WTl[o] = lo;
}

// ---------------- encoder ----------------
__global__ void k_enc_agg(const float4* __restrict__ x4, const int* __restrict__ rs,
                          const int* __restrict__ csr, const float* __restrict__ dis,
                          float4* __restrict__ zx, int n) {
    int i = blockIdx.x * 256 + threadIdx.x;
    if (i >= n) return;
    float4 a = x4[i];
    int e1 = rs[i + 1];
    for (int j = rs[i]; j < e1; ++j) {
        float4 v = x4[csr[j]];
        a.x += v.x; a.y += v.y; a.z += v.z;
    }
    float d = dis[i];
    zx[i] = make_float4(a.x * d, a.y * d, a.z * d, 0.f);
}

__global__ void k_enc_gemm(const float4* __restrict__ zx, const float* __restrict__ We,
                           const float* __restrict__ be, const float* __restrict__ dis,
                           __half* __restrict__ H, int n) {
    int t = blockIdx.x * 256 + threadIdx.x;
    int i = t >> 7;
    int c = t & 127;
    if (i >= n) return;
    float4 z = zx[i];
    float v = z.x * We[c] + z.y * We[HW + c] + z.z * We[2 * HW + c] + be[c];
    H[(size_t)i * HW + c] = __float2half_rn(fmaxf(v, 0.f) * dis[i]);
}

// ---------------- width-128 aggregate: 4 nodes/wave, 16 lanes/node ----------
// Lane covers 8 features (16B). One gather instruction = 4 rows = 1KB.
// Z[i] = fp16( dis_i * ( H'[i] + sum_src H'[src] ) )
__global__ __launch_bounds__(256) void k_agg128(const __half* __restrict__ Hin,
                                                const int* __restrict__ rs,
                                                const int* __restrict__ csr,
                                                const float* __restrict__ dis,
                                                __half* __restrict__ Z, int n) {
    int wave = threadIdx.x >> 6, lane = threadIdx.x & 63;
    int lg = lane & 15;  // lane in 16-lane group
    int node = (blockIdx.x * 4 + wave) * 4 + (lane >> 4);
    bool active = node < n;

    float a0[8], a1[8], a2[8], a3[8];
#pragma unroll
    for (int j = 0; j < 8; ++j) { a0[j] = 0.f; a1[j] = 0.f; a2[j] = 0.f; a3[j] = 0.f; }

    int e0 = 0, e1 = 0;
    if (active) {
        e0 = rs[node];
        e1 = rs[node + 1];
        f16x8 hv = *(const f16x8*)(Hin + (size_t)node * HW + lg * 8);
#pragma unroll
        for (int j = 0; j < 8; ++j) a0[j] = (float)hv[j];
    }

    for (int base = e0; base < e1; base += 16) {
        int cnt = e1 - base;
        if (cnt > 16) cnt = 16;
        int sl = (base + lg < e1) ? csr[base + lg] : 0;
        int k = 0;
        for (; k + 4 <= cnt; k += 4) {
            int s0 = __shfl(sl, k + 0, 16);
            int s1 = __shfl(sl, k + 1, 16);
            int s2 = __shfl(sl, k + 2, 16);
            int s3 = __shfl(sl, k + 3, 16);
            f16x8 v0 = *(const f16x8*)(Hin + (size_t)s0 * HW + lg * 8);
            f16x8 v1 = *(const f16x8*)(Hin + (size_t)s1 * HW + lg * 8);
            f16x8 v2 = *(const f16x8*)(Hin + (size_t)s2 * HW + lg * 8);
            f16x8 v3 = *(const f16x8*)(Hin + (size_t)s3 * HW + lg * 8);
#pragma unroll
            for (int j = 0; j < 8; ++j) {
                a0[j] += (float)v0[j];
                a1[j] += (float)v1[j];
                a2[j] += (float)v2[j];
                a3[j] += (float)v3[j];
            }
        }
        for (; k < cnt; ++k) {
            int s = __shfl(sl, k, 16);
            f16x8 v = *(const f16x8*)(Hin + (size_t)s * HW + lg * 8);
#pragma unroll
            for (int j = 0; j < 8; ++j) a0[j] += (float)v[j];
        }
    }

    if (active) {
        float d = dis[node];
        union { uint4 u; __half2 h[4]; } pk;
#pragma unroll
        for (int j = 0; j < 4; ++j) {
            float lo = d * ((a0[2 * j] + a1[2 * j]) + (a2[2 * j] + a3[2 * j]));
            float hi = d * ((a0[2 * j + 1] + a1[2 * j + 1]) + (a2[2 * j + 1] + a3[2 * j + 1]));
            pk.h[j] = __floats2half2_rn(lo, hi);
        }
        *(uint4*)(Z + (size_t)node * HW + lg * 8) = pk.u;
    }
}

// ---------------- MFMA GEMM: H' = dis * relu(Z @ W + b), in place -----------
// mode 0: write fp16 H'. mode 1 (last layer): skip H, emit t[row] = H'.Wd.
// Layout (16x16x32): A row=lane&15, k=(lane>>4)*8+j ; B col=lane&15, same k;
// C/D col=lane&15, row=(lane>>4)*4+reg.
#define GBM 256
__global__ __launch_bounds__(256) void k_gemm_mfma(const __half* __restrict__ Z,
                                                   const __half* __restrict__ WTh,
                                                   const __half* __restrict__ WTl,
                                                   const float* __restrict__ b,
                                                   const float* __restrict__ dis,
                                                   __half* __restrict__ Hout,
                                                   const float* __restrict__ Wd,
                                                   float* __restrict__ tout,
                                                   int mode, int n) {
    int wave = threadIdx.x >> 6, lane = threadIdx.x & 63;
    int q = lane >> 4, r16 = lane & 15;
    int row0 = blockIdx.x * GBM + wave * 64;

    f32x4 acc[4][8];
#pragma unroll
    for (int mt = 0; mt < 4; ++mt)
#pragma unroll
        for (int nt = 0; nt < 8; ++nt) acc[mt][nt] = (f32x4)0.f;

#pragma unroll
    for (int ks = 0; ks < 4; ++ks) {
        f16x8 afr[4];
#pragma unroll
        for (int mt = 0; mt < 4; ++mt) {
            int row = row0 + mt * 16 + r16;
            row = row < n ? row : (n - 1);  // clamp; results discarded at store
            afr[mt] = *(const f16x8*)(Z + (size_t)row * HW + ks * 32 + q * 8);
        }
#pragma unroll
        for (int nt = 0; nt < 8; ++nt) {
            f16x8 bh = *(const f16x8*)(WTh + (size_t)(nt * 16 + r16) * HW + ks * 32 + q * 8);
            f16x8 bl = *(const f16x8*)(WTl + (size_t)(nt * 16 + r16) * HW + ks * 32 + q * 8);
#pragma unroll
            for (int mt = 0; mt < 4; ++mt) {
                acc[mt][nt] = __builtin_amdgcn_mfma_f32_16x16x32_f16(afr[mt], bh, acc[mt][nt], 0, 0, 0);
                acc[mt][nt] = __builtin_amdgcn_mfma_f32_16x16x32_f16(afr[mt], bl, acc[mt][nt], 0, 0, 0);
            }
        }
    }

    float dr[4][4];
#pragma unroll
    for (int mt = 0; mt < 4; ++mt)
#pragma unroll
        for (int r = 0; r < 4; ++r) {
            int row = row0 + mt * 16 + q * 4 + r;
            dr[mt][r] = (row < n) ? dis[row] : 0.f;
        }
    float bias[8];
#pragma unroll
    for (int nt = 0; nt < 8; ++nt) bias[nt] = b[nt * 16 + r16];

    if (mode == 0) {
#pragma unroll
        for (int nt = 0; nt < 8; ++nt) {
#pragma unroll
            for (int mt = 0; mt < 4; ++mt) {
#pragma unroll
                for (int r = 0; r < 4; ++r) {
                    int row = row0 + mt * 16 + q * 4 + r;
                    if (row < n) {
                        float v = fmaxf(acc[mt][nt][r] + bias[nt], 0.f) * dr[mt][r];
                        Hout[(size_t)row * HW + nt * 16 + r16] = __float2half_rn(v);
                    }
                }
            }
        }
    } else {
        float wd[8];
#pragma unroll
        for (int nt = 0; nt < 8; ++nt) wd[nt] = Wd[nt * 16 + r16];
#pragma unroll
        for (int mt = 0; mt < 4; ++mt) {
#pragma unroll
            for (int r = 0; r < 4; ++r) {
                float pr = 0.f;
#pragma unroll
                for (int nt = 0; nt < 8; ++nt)
                    pr += fmaxf(acc[mt][nt][r] + bias[nt], 0.f) * wd[nt];
                pr *= dr[mt][r];
#pragma unroll
                for (int off = 1; off < 16; off <<= 1) pr += __shfl_xor(pr, off, 16);
                if (r16 == 0) {
                    int row = row0 + mt * 16 + q * 4 + r;
                    if (row < n) tout[row] = pr;
                }
            }
        }
    }
}

// ---------------- decoder output ----------------
// out[i] = (dis_i * (sum_src t[src] + t[i]) + b) * mask[i]
__global__ void k_dec_out(const float* __restrict__ t, const int* __restrict__ rs,
                          const int* __restrict__ csr, const float* __restrict__ dis,
                          const float* __restrict__ bdec, const float* __restrict__ mask,
                          float* __restrict__ out, int n) {
    int i = blockIdx.x * 256 + threadIdx.x;
    if (i >= n) return;
    float acc = t[i];
    int e1 = rs[i + 1];
    for (int j = rs[i]; j < e1; ++j) acc += t[csr[j]];
    out[i] = (dis[i] * acc + bdec[0]) * mask[i];
}

// ---------------------------------------------------------------------------
static inline size_t align256(size_t x) { return (x + 255) & ~(size_t)255; }

extern "C" void kernel_launch(void* const* d_in, const int* in_sizes, int n_in,
                              void* d_out, int out_size, void* d_ws, size_t ws_size,
                              hipStream_t stream) {
    const float* x     = (const float*)d_in[0];
    const float* mask  = (const float*)d_in[1];
    const int*   ei    = (const int*)d_in[2];
    const float* W_enc = (const float*)d_in[3];
    const float* b_enc = (const float*)d_in[4];
    const float* W_p   = (const float*)d_in[5];
    const float* b_p   = (const float*)d_in[6];
    const float* W_dec = (const float*)d_in[7];
    const float* b_dec = (const float*)d_in[8];

    const int N = in_sizes[1];
    const int E = in_sizes[2] / 2;
    const int* srcA = ei;
    const int* dstA = ei + E;
    const int NB = (N + 127) >> 7;  // dst buckets of 128 nodes

    char* p = (char*)d_ws;
    size_t off = 0;
    auto carve = [&](size_t bytes) {
        void* r = p + off;
        off += align256(bytes);
        return r;
    };
    int*    deg       = (int*)carve((size_t)N * 4);
    int*    cursor    = (int*)carve((size_t)N * 4);
    int*    row_start = (int*)carve((size_t)(N + 1) * 4);
    int*    bsum      = (int*)carve(512 * 4);
    int*    scnt      = (int*)carve((size_t)8 * NB * 4);
    int*    soff      = (int*)carve((size_t)8 * NB * 4);
    int*    csr       = (int*)carve((size_t)E * 4);
    int2*   stage     = (int2*)carve((size_t)E * 8);
    float*  dis       = (float*)carve((size_t)N * 4);
    float4* x4        = (float4*)carve((size_t)N * 16);
    float4* zx        = (float4*)carve((size_t)N * 16);  // also scan tmp
    float*  tdec      = (float*)carve((size_t)N * 4);
    __half* WTh       = (__half*)carve((size_t)4 * HW * HW * 2);
    __half* WTl       = (__half*)carve((size_t)4 * HW * HW * 2);
    __half* HA        = (__half*)carve((size_t)N * HW * 2);
    __half* HB        = (__half*)carve((size_t)N * HW * 2);
    int*    tmp       = (int*)zx;

    const int gN   = (N + 255) / 256;
    const int gE   = (E + 255) / 256;
    const int gNB  = (NB + 255) / 256;
    const int gAgg = (N + 15) / 16;
    const int gG   = (N + GBM - 1) / GBM;
    const int WPT  = 4 * HW * HW;

    // ---- CSR build (two-pass radix partition) + preps ----
    k_zero_i32<<<gN, 256, 0, stream>>>(deg, N);
    k_zero_i32<<<(8 * NB + 255) / 256, 256, 0, stream>>>(scnt, 8 * NB);
    k_hist<<<gE, 256, 0, stream>>>(dstA, deg, scnt, NB, E);
    k_scan_a<<<gN, 256, 0, stream>>>(deg, tmp, bsum, dis, N);
    k_scan_b<<<1, 512, 0, stream>>>(bsum, gN);
    k_scan_c<<<gN, 256, 0, stream>>>(tmp, deg, bsum, row_start, cursor, N, E);
    k_soff<<<gNB, 256, 0, stream>>>(scnt, row_start, soff, NB);
    k_part<<<gE, 256, 0, stream>>>(srcA, dstA, soff, stage, NB, E);
    k_scatter2<<<gE, 256, 0, stream>>>(stage, row_start, cursor, csr, E);
    k_prep_x<<<gN, 256, 0, stream>>>(x, dis, x4, N);
    k_prep_wt<<<(WPT + 255) / 256, 256, 0, stream>>>(W_p, WTh, WTl, WPT);

    // ---- encoder ----
    k_enc_agg<<<gN, 256, 0, stream>>>(x4, row_start, csr, dis, zx, N);
    k_enc_gemm<<<(N * HW + 255) / 256, 256, 0, stream>>>(zx, W_enc, b_enc, dis, HA, N);

    // ---- 4 processor layers: agg(Hin->Hoth), gemm in place on Hoth ----
    // Last layer's gemm emits the decoder matvec t directly (mode 1).
    __half* Hin = HA;
    __half* Hoth = HB;
    for (int l = 0; l < 4; ++l) {
        k_agg128<<<gAgg, 256, 0, stream>>>(Hin, row_start, csr, dis, Hoth, N);
        int mode = (l == 3) ? 1 : 0;
        k_gemm_mfma<<<gG, 256, 0, stream>>>(Hoth, WTh + (size_t)l * HW * HW,
                                            WTl + (size_t)l * HW * HW,
                                            b_p + (size_t)l * HW, dis, Hoth,
                                            W_dec, tdec, mode, N);
        __half* t = Hin; Hin = Hoth; Hoth = t;
    }

    // ---- decoder output ----
    k_dec_out<<<gN, 256, 0, stream>>>(tdec, row_start, csr, dis, b_dec, mask,
                                      (float*)d_out, N);
}

// Round 8
// 514.009 us; speedup vs baseline: 1.4677x; 1.4677x over previous
//
#include <hip/hip_runtime.h>
#include <hip/hip_fp16.h>

// ---------------------------------------------------------------------------
// MaskedGNN: 6-layer GCN, weight-free scaled-hidden formulation.
//  Store H' = dis * h  (fp16). Per layer:
//    z_i = dis_i * ( sum_{src in N(i)} H'_src + H'_i )   [pure gather-sum]
//    h_next' = dis * relu(z @ W + b)
//  CSR build: LDS-histogram radix partition by bucket = dst>>7 (128 nodes,
//  8KB csr window). Only ~200K coarse global atomics (range reservations);
//  all bulk global writes are dense/coalesced. k_build also emits row_start,
//  dis and the prescaled encoder input x4 (per-bucket, coalesced).
//  GEMM: MFMA f32_16x16x32_f16, W split hi/lo fp16 (W exact), fp32 accum,
//  in-place. Last GEMM fuses the decoder matvec.
// ---------------------------------------------------------------------------

#define HW 128     // hidden width
#define NBMAX 1024 // max dst buckets (N <= 131072)
#define CAP 4096   // max edges per bucket staged in LDS (mean 2048, sigma ~45)

typedef _Float16 f16x8 __attribute__((ext_vector_type(8)));
typedef float f32x4 __attribute__((ext_vector_type(4)));

// ---------------- CSR build ----------------
__global__ void k_zero_i32(int* __restrict__ a, int n) {
    int i = blockIdx.x * 256 + threadIdx.x;
    if (i < n) a[i] = 0;
}

// per-block LDS bucket histogram; one flush atomic per (block,bucket)
__global__ __launch_bounds__(256) void k_histb(const int* __restrict__ dstA,
                                               int* __restrict__ bcnt,
                                               int nb, int e, int nblk) {
    __shared__ int lh[NBMAX];
    for (int b = threadIdx.x; b < nb; b += 256) lh[b] = 0;
    __syncthreads();
    int blk = blockIdx.x;
    int c0 = (int)(((long long)e * blk) / nblk);
    int c1 = (int)(((long long)e * (blk + 1)) / nblk);
    for (int i = c0 + threadIdx.x; i < c1; i += 256) atomicAdd(&lh[dstA[i] >> 7], 1);
    __syncthreads();
    for (int b = threadIdx.x; b < nb; b += 256) {
        int v = lh[b];
        if (v) atomicAdd(&bcnt[b], v);
    }
}

// exclusive scan of bucket counts -> bucket windows; init bucket cursors
__global__ void k_bscan(const int* __restrict__ bcnt, int* __restrict__ bstart,
                        int* __restrict__ bcur, int nb, int etot) {
    __shared__ int s[1024];
    int t = threadIdx.x;
    int d0 = (t < nb) ? bcnt[t] : 0;
    s[t] = d0;
    __syncthreads();
    for (int off = 1; off < 1024; off <<= 1) {
        int v = (t >= off) ? s[t - off] : 0;
        __syncthreads();
        s[t] += v;
        __syncthreads();
    }
    if (t < nb) {
        int ex = s[t] - d0;
        bstart[t] = ex;
        bcur[t] = ex;
    }
    if (t == 0) bstart[nb] = etot;
}

// partition edges into bucket windows; per-block LDS hist -> one reservation
// atomic per (block,bucket) -> LDS-cursor placement. stage = (src<<7)|(dst&127).
__global__ __launch_bounds__(256) void k_part(const int* __restrict__ srcA,
                                              const int* __restrict__ dstA,
                                              int* __restrict__ bcur,
                                              unsigned* __restrict__ stage,
                                              int nb, int e, int nblk) {
    __shared__ int lh[NBMAX];
    __shared__ int loff[NBMAX];
    for (int b = threadIdx.x; b < nb; b += 256) lh[b] = 0;
    __syncthreads();
    int blk = blockIdx.x;
    int c0 = (int)(((long long)e * blk) / nblk);
    int c1 = (int)(((long long)e * (blk + 1)) / nblk);
    for (int i = c0 + threadIdx.x; i < c1; i += 256) atomicAdd(&lh[dstA[i] >> 7], 1);
    __syncthreads();
    for (int b = threadIdx.x; b < nb; b += 256) {
        int v = lh[b];
        loff[b] = v ? atomicAdd(&bcur[b], v) : 0;
    }
    __syncthreads();
    for (int b = threadIdx.x; b < nb; b += 256) lh[b] = 0;
    __syncthreads();
    for (int i = c0 + threadIdx.x; i < c1; i += 256) {
        int d = dstA[i];
        int bk = d >> 7;
        int p = loff[bk] + atomicAdd(&lh[bk], 1);
        stage[p] = ((unsigned)srcA[i] << 7) | (unsigned)(d & 127);
    }
}

// one block per bucket: local count+scan -> row_start/dis/x4 (coalesced),
// LDS placement of srcs -> coalesced csr window write.
__global__ __launch_bounds__(256) void k_build(const unsigned* __restrict__ stage,
                                               const int* __restrict__ bstart,
                                               const float* __restrict__ x,
                                               int* __restrict__ row_start,
                                               float* __restrict__ dis,
                                               float4* __restrict__ x4,
                                               int* __restrict__ csr, int n, int nb) {
    __shared__ int lcnt[128];
    __shared__ int sc[128];
    __shared__ int lcsr[CAP];
    int b = blockIdx.x, tid = threadIdx.x;
    int base = bstart[b], end = bstart[b + 1], cnt = end - base;
    int node0 = b << 7;

    if (tid < 128) lcnt[tid] = 0;
    __syncthreads();
    for (int j = tid; j < cnt; j += 256) atomicAdd(&lcnt[stage[base + j] & 127], 1);
    __syncthreads();
    if (tid < 128) sc[tid] = lcnt[tid];
    __syncthreads();
    for (int off = 1; off < 128; off <<= 1) {
        int v = (tid < 128 && tid >= off) ? sc[tid - off] : 0;
        __syncthreads();
        if (tid < 128) sc[tid] += v;
        __syncthreads();
    }
    int node = node0 + tid;
    if (tid < 128 && node < n) {
        int excl = sc[tid] - lcnt[tid];
        row_start[node] = base + excl;
        float dv = rsqrtf(1.f + (float)lcnt[tid]);
        dis[node] = dv;
        x4[node] = make_float4(x[node * 3] * dv, x[node * 3 + 1] * dv,
                               x[node * 3 + 2] * dv, 0.f);
    }
    if (tid == 0 && b == nb - 1) row_start[n] = end;
    __syncthreads();
    if (tid < 128) sc[tid] = sc[tid] - lcnt[tid];  // exclusive offsets
    __syncthreads();
    if (tid < 128) lcnt[tid] = 0;
    __syncthreads();
    if (cnt <= CAP) {
        for (int j = tid; j < cnt; j += 256) {
            unsigned v = stage[base + j];
            int dl = v & 127;
            int p = atomicAdd(&lcnt[dl], 1);
            lcsr[sc[dl] + p] = (int)(v >> 7);
        }
        __syncthreads();
        for (int j = tid; j < cnt; j += 256) csr[base + j] = lcsr[j];
    } else {  // pathological bucket: direct (rare/never for this N,E)
        for (int j = tid; j < cnt; j += 256) {
            unsigned v = stage[base + j];
            int dl = v & 127;
            int p = atomicAdd(&lcnt[dl], 1);
            csr[base + sc[dl] + p] = (int)(v >> 7);
        }
    }
}

// ---------------- W prep: transpose + hi/lo fp16 split ----------------
__global__ void k_prep_wt(const float* __restrict__ Wp, __half* __restrict__ WTh,
                          __half* __restrict__ WTl, int total) {
    int t = blockIdx.x * 256 + threadIdx.x;
    if (t >= total) return;
    int l = t >> 14;
    int kc = t & 16383;
    int k = kc >> 7, c = kc & 127;
    float w = Wp[t];
    __half hi = __float2half_rn(w);
    __half lo = __float2half_rn(w - __half2float(hi));
    size_t o = ((size_t)l << 14) + (size_t)c * HW + k;
    WTh[o] = hi;
    WTl[o] = lo;
}

// ---------------- encoder ----------------
__global__ void k_enc_agg(const float4* __restrict__ x4, const int* __restrict__ rs,
                          const int* __restrict__ csr, const float* __restrict__ dis,
                          float4* __restrict__ zx, int n) {
    int i = blockIdx.x * 256 + threadIdx.x;
    if (i >= n) return;
    float4 a = x4[i];
    int e1 = rs[i + 1];
    for (int j = rs[i]; j < e1; ++j) {
        float4 v = x4[csr[j]];
        a.x += v.x; a.y += v.y; a.z += v.z;
    }
    float d = dis[i];
    zx[i] = make_float4(a.x * d, a.y * d, a.z * d, 0.f);
}

__global__ void k_enc_gemm(const float4* __restrict__ zx, const float* __restrict__ We,
                           const float* __restrict__ be, const float* __restrict__ dis,
                           __half* __restrict__ H, int n) {
    int t = blockIdx.x * 256 + threadIdx.x;
    int i = t >> 7;
    int c = t & 127;
    if (i >= n) return;
    float4 z = zx[i];
    float v = z.x * We[c] + z.y * We[HW + c] + z.z * We[2 * HW + c] + be[c];
    H[(size_t)i * HW + c] = __float2half_rn(fmaxf(v, 0.f) * dis[i]);
}

// ---------------- width-128 aggregate: 4 nodes/wave, 16 lanes/node ----------
// Lane covers 8 features (16B). One gather instruction = 4 rows = 1KB.
// Z[i] = fp16( dis_i * ( H'[i] + sum_src H'[src] ) )
__global__ __launch_bounds__(256) void k_agg128(const __half* __restrict__ Hin,
                                                const int* __restrict__ rs,
                                                const int* __restrict__ csr,
                                                const float* __restrict__ dis,
                                                __half* __restrict__ Z, int n) {
    int wave = threadIdx.x >> 6, lane = threadIdx.x & 63;
    int lg = lane & 15;  // lane in 16-lane group
    int node = (blockIdx.x * 4 + wave) * 4 + (lane >> 4);
    bool active = node < n;

    float a0[8], a1[8], a2[8], a3[8];
#pragma unroll
    for (int j = 0; j < 8; ++j) { a0[j] = 0.f; a1[j] = 0.f; a2[j] = 0.f; a3[j] = 0.f; }

    int e0 = 0, e1 = 0;
    if (active) {
        e0 = rs[node];
        e1 = rs[node + 1];
        f16x8 hv = *(const f16x8*)(Hin + (size_t)node * HW + lg * 8);
#pragma unroll
        for (int j = 0; j < 8; ++j) a0[j] = (float)hv[j];
    }

    for (int base = e0; base < e1; base += 16) {
        int cnt = e1 - base;
        if (cnt > 16) cnt = 16;
        int sl = (base + lg < e1) ? csr[base + lg] : 0;
        int k = 0;
        for (; k + 4 <= cnt; k += 4) {
            int s0 = __shfl(sl, k + 0, 16);
            int s1 = __shfl(sl, k + 1, 16);
            int s2 = __shfl(sl, k + 2, 16);
            int s3 = __shfl(sl, k + 3, 16);
            f16x8 v0 = *(const f16x8*)(Hin + (size_t)s0 * HW + lg * 8);
            f16x8 v1 = *(const f16x8*)(Hin + (size_t)s1 * HW + lg * 8);
            f16x8 v2 = *(const f16x8*)(Hin + (size_t)s2 * HW + lg * 8);
            f16x8 v3 = *(const f16x8*)(Hin + (size_t)s3 * HW + lg * 8);
#pragma unroll
            for (int j = 0; j < 8; ++j) {
                a0[j] += (float)v0[j];
                a1[j] += (float)v1[j];
                a2[j] += (float)v2[j];
                a3[j] += (float)v3[j];
            }
        }
        for (; k < cnt; ++k) {
            int s = __shfl(sl, k, 16);
            f16x8 v = *(const f16x8*)(Hin + (size_t)s * HW + lg * 8);
#pragma unroll
            for (int j = 0; j < 8; ++j) a0[j] += (float)v[j];
        }
    }

    if (active) {
        float d = dis[node];
        union { uint4 u; __half2 h[4]; } pk;
#pragma unroll
        for (int j = 0; j < 4; ++j) {
            float lo = d * ((a0[2 * j] + a1[2 * j]) + (a2[2 * j] + a3[2 * j]));
            float hi = d * ((a0[2 * j + 1] + a1[2 * j + 1]) + (a2[2 * j + 1] + a3[2 * j + 1]));
            pk.h[j] = __floats2half2_rn(lo, hi);
        }
        *(uint4*)(Z + (size_t)node * HW + lg * 8) = pk.u;
    }
}

// ---------------- MFMA GEMM: H' = dis * relu(Z @ W + b), in place -----------
// mode 0: write fp16 H'. mode 1 (last layer): skip H, emit t[row] = H'.Wd.
// Layout (16x16x32): A row=lane&15, k=(lane>>4)*8+j ; B col=lane&15, same k;
// C/D col=lane&15, row=(lane>>4)*4+reg.
#define GBM 256
__global__ __launch_bounds__(256) void k_gemm_mfma(const __half* __restrict__ Z,
                                                   const __half* __restrict__ WTh,
                                                   const __half* __restrict__ WTl,
                                                   const float* __restrict__ b,
                                                   const float* __restrict__ dis,
                                                   __half* __restrict__ Hout,
                                                   const float* __restrict__ Wd,
                                                   float* __restrict__ tout,
                                                   int mode, int n) {
    int wave = threadIdx.x >> 6, lane = threadIdx.x & 63;
    int q = lane >> 4, r16 = lane & 15;
    int row0 = blockIdx.x * GBM + wave * 64;

    f32x4 acc[4][8];
#pragma unroll
    for (int mt = 0; mt < 4; ++mt)
#pragma unroll
        for (int nt = 0; nt < 8; ++nt) acc[mt][nt] = (f32x4)0.f;

#pragma unroll
    for (int ks = 0; ks < 4; ++ks) {
        f16x8 afr[4];
#pragma unroll
        for (int mt = 0; mt < 4; ++mt) {
            int row = row0 + mt * 16 + r16;
            row = row < n ? row : (n - 1);  // clamp; results discarded at store
            afr[mt] = *(const f16x8*)(Z + (size_t)row * HW + ks * 32 + q * 8);
        }
#pragma unroll
        for (int nt = 0; nt < 8; ++nt) {
            f16x8 bh = *(const f16x8*)(WTh + (size_t)(nt * 16 + r16) * HW + ks * 32 + q * 8);
            f16x8 bl = *(const f16x8*)(WTl + (size_t)(nt * 16 + r16) * HW + ks * 32 + q * 8);
#pragma unroll
            for (int mt = 0; mt < 4; ++mt) {
                acc[mt][nt] = __builtin_amdgcn_mfma_f32_16x16x32_f16(afr[mt], bh, acc[mt][nt], 0, 0, 0);
                acc[mt][nt] = __builtin_amdgcn_mfma_f32_16x16x32_f16(afr[mt], bl, acc[mt][nt], 0, 0, 0);
            }
        }
    }

    float dr[4][4];
#pragma unroll
    for (int mt = 0; mt < 4; ++mt)
#pragma unroll
        for (int r = 0; r < 4; ++r) {
            int row = row0 + mt * 16 + q * 4 + r;
            dr[mt][r] = (row < n) ? dis[row] : 0.f;
        }
    float bias[8];
#pragma unroll
    for (int nt = 0; nt < 8; ++nt) bias[nt] = b[nt * 16 + r16];

    if (mode == 0) {
#pragma unroll
        for (int nt = 0; nt < 8; ++nt) {
#pragma unroll
            for (int mt = 0; mt < 4; ++mt) {
#pragma unroll
                for (int r = 0; r < 4; ++r) {
                    int row = row0 + mt * 16 + q * 4 + r;
                    if (row < n) {
                        float v = fmaxf(acc[mt][nt][r] + bias[nt], 0.f) * dr[mt][r];
                        Hout[(size_t)row * HW + nt * 16 + r16] = __float2half_rn(v);
                    }
                }
            }
        }
    } else {
        float wd[8];
#pragma unroll
        for (int nt = 0; nt < 8; ++nt) wd[nt] = Wd[nt * 16 + r16];
#pragma unroll
        for (int mt = 0; mt < 4; ++mt) {
#pragma unroll
            for (int r = 0; r < 4; ++r) {
                float pr = 0.f;
#pragma unroll
                for (int nt = 0; nt < 8; ++nt)
                    pr += fmaxf(acc[mt][nt][r] + bias[nt], 0.f) * wd[nt];
                pr *= dr[mt][r];
#pragma unroll
                for (int off = 1; off < 16; off <<= 1) pr += __shfl_xor(pr, off, 16);
                if (r16 == 0) {
                    int row = row0 + mt * 16 + q * 4 + r;
                    if (row < n) tout[row] = pr;
                }
            }
        }
    }
}

// ---------------- decoder output ----------------
// out[i] = (dis_i * (sum_src t[src] + t[i]) + b) * mask[i]
__global__ void k_dec_out(const float* __restrict__ t, const int* __restrict__ rs,
                          const int* __restrict__ csr, const float* __restrict__ dis,
                          const float* __restrict__ bdec, const float* __restrict__ mask,
                          float* __restrict__ out, int n) {
    int i = blockIdx.x * 256 + threadIdx.x;
    if (i >= n) return;
    float acc = t[i];
    int e1 = rs[i + 1];
    for (int j = rs[i]; j < e1; ++j) acc += t[csr[j]];
    out[i] = (dis[i] * acc + bdec[0]) * mask[i];
}

// ---------------------------------------------------------------------------
static inline size_t align256(size_t x) { return (x + 255) & ~(size_t)255; }

extern "C" void kernel_launch(void* const* d_in, const int* in_sizes, int n_in,
                              void* d_out, int out_size, void* d_ws, size_t ws_size,
                              hipStream_t stream) {
    const float* x     = (const float*)d_in[0];
    const float* mask  = (const float*)d_in[1];
    const int*   ei    = (const int*)d_in[2];
    const float* W_enc = (const float*)d_in[3];
    const float* b_enc = (const float*)d_in[4];
    const float* W_p   = (const float*)d_in[5];
    const float* b_p   = (const float*)d_in[6];
    const float* W_dec = (const float*)d_in[7];
    const float* b_dec = (const float*)d_in[8];

    const int N = in_sizes[1];
    const int E = in_sizes[2] / 2;
    const int* srcA = ei;
    const int* dstA = ei + E;
    const int NB = (N + 127) >> 7;  // dst buckets of 128 nodes (NB <= NBMAX)

    char* p = (char*)d_ws;
    size_t off = 0;
    auto carve = [&](size_t bytes) {
        void* r = p + off;
        off += align256(bytes);
        return r;
    };
    int*      bcnt      = (int*)carve((size_t)NB * 4);
    int*      bstart    = (int*)carve((size_t)(NB + 1) * 4);
    int*      bcur      = (int*)carve((size_t)NB * 4);
    int*      row_start = (int*)carve((size_t)(N + 1) * 4);
    unsigned* stage     = (unsigned*)carve((size_t)E * 4);
    int*      csr       = (int*)carve((size_t)E * 4);
    float*    dis       = (float*)carve((size_t)N * 4);
    float4*   x4        = (float4*)carve((size_t)N * 16);
    float4*   zx        = (float4*)carve((size_t)N * 16);
    float*    tdec      = (float*)carve((size_t)N * 4);
    __half*   WTh       = (__half*)carve((size_t)4 * HW * HW * 2);
    __half*   WTl       = (__half*)carve((size_t)4 * HW * HW * 2);
    __half*   HA        = (__half*)carve((size_t)N * HW * 2);
    __half*   HB        = (__half*)carve((size_t)N * HW * 2);

    const int gN    = (N + 255) / 256;
    const int gAgg  = (N + 15) / 16;
    const int gG    = (N + GBM - 1) / GBM;
    const int WPT   = 4 * HW * HW;
    const int PBLK  = 256;  // blocks for histb/part

    // ---- CSR build (LDS-histogram radix partition) ----
    k_zero_i32<<<(NB + 255) / 256, 256, 0, stream>>>(bcnt, NB);
    k_histb<<<PBLK, 256, 0, stream>>>(dstA, bcnt, NB, E, PBLK);
    k_bscan<<<1, 1024, 0, stream>>>(bcnt, bstart, bcur, NB, E);
    k_part<<<PBLK, 256, 0, stream>>>(srcA, dstA, bcur, stage, NB, E, PBLK);
    k_build<<<NB, 256, 0, stream>>>(stage, bstart, x, row_start, dis, x4, csr, N, NB);
    k_prep_wt<<<(WPT + 255) / 256, 256, 0, stream>>>(W_p, WTh, WTl, WPT);

    // ---- encoder ----
    k_enc_agg<<<gN, 256, 0, stream>>>(x4, row_start, csr, dis, zx, N);
    k_enc_gemm<<<(N * HW + 255) / 256, 256, 0, stream>>>(zx, W_enc, b_enc, dis, HA, N);

    // ---- 4 processor layers: agg(Hin->Hoth), gemm in place on Hoth ----
    // Last layer's gemm emits the decoder matvec t directly (mode 1).
    __half* Hin = HA;
    __half* Hoth = HB;
    for (int l = 0; l < 4; ++l) {
        k_agg128<<<gAgg, 256, 0, stream>>>(Hin, row_start, csr, dis, Hoth, N);
        int mode = (l == 3) ? 1 : 0;
        k_gemm_mfma<<<gG, 256, 0, stream>>>(Hoth, WTh + (size_t)l * HW * HW,
                                            WTl + (size_t)l * HW * HW,
                                            b_p + (size_t)l * HW, dis, Hoth,
                                            W_dec, tdec, mode, N);
        __half* t = Hin; Hin = Hoth; Hoth = t;
    }

    // ---- decoder output ----
    k_dec_out<<<gN, 256, 0, stream>>>(tdec, row_start, csr, dis, b_dec, mask,
                                      (float*)d_out, N);
}